// Round 3
// baseline (446.969 us; speedup 1.0000x reference)
//
#include <hip/hip_runtime.h>

// BagRE: segment-mean over sorted bags + linear classifier, fused.
//   hidden [N=262144, H=256] f32, W [C=128, H=256] f32, b [C] f32,
//   bag_id [N] i32 (sorted)  ->  out [NUM_BAGS=8192, C=128] f32
//
// R2 lesson: dur_us (388) = constant harness overhead (1 GB ws-poison fill
// ~160 us + 256 MB input restore + ...) + kernel time X. Kernel is absent
// from rocprof top-5 (all slots are ~160 us fills) => X < ~159 us, but X is
// otherwise unknown. THIS ROUND IS A PROBE: launch the identical kernel
// TWICE (idempotent, deterministic) so X = dur_R3 - dur_R2 exactly.

#define NBAGS 8192
#define HDIM 256
#define CDIM 128
#define BPB 8  // bags per block

__global__ __launch_bounds__(256) void bagre_kernel(
    const float* __restrict__ hidden,
    const float* __restrict__ W,
    const float* __restrict__ b,
    const int* __restrict__ bag_id,
    float* __restrict__ out,
    int N)
{
    __shared__ __align__(16) float s_mean[BPB][HDIM];   // 8 KB
    __shared__ float s_part[2][BPB][CDIM];              // 8 KB
    __shared__ int s_bound[BPB + 1];

    const int t  = threadIdx.x;
    const int g0 = blockIdx.x * BPB;

    // --- segment boundaries: bag_id is sorted; lower_bound(g0 + t) ---
    if (t <= BPB) {
        const int target = g0 + t;
        int lo = 0, hi = N;
        while (lo < hi) {
            const int mid = (lo + hi) >> 1;
            if (bag_id[mid] < target) lo = mid + 1; else hi = mid;
        }
        s_bound[t] = lo;
    }
    __syncthreads();

    // --- phase 1: wave q owns bags 2q and 2q+1; no cross-wave reduce ---
    const int q    = t >> 6;
    const int lane = t & 63;
    const int col4 = lane << 2;

#pragma unroll
    for (int jj = 0; jj < 2; ++jj) {
        const int j = q * 2 + jj;
        const int s = s_bound[j];
        const int e = s_bound[j + 1];

        float4 a0 = make_float4(0.f, 0.f, 0.f, 0.f);
        float4 a1 = a0, a2 = a0, a3 = a0;

        const float* __restrict__ p = hidden + (size_t)s * HDIM + col4;
        int r = s;
        for (; r + 4 <= e; r += 4, p += 4 * HDIM) {
            const float4 v0 = *(const float4*)(p + 0 * HDIM);
            const float4 v1 = *(const float4*)(p + 1 * HDIM);
            const float4 v2 = *(const float4*)(p + 2 * HDIM);
            const float4 v3 = *(const float4*)(p + 3 * HDIM);
            a0.x += v0.x; a0.y += v0.y; a0.z += v0.z; a0.w += v0.w;
            a1.x += v1.x; a1.y += v1.y; a1.z += v1.z; a1.w += v1.w;
            a2.x += v2.x; a2.y += v2.y; a2.z += v2.z; a2.w += v2.w;
            a3.x += v3.x; a3.y += v3.y; a3.z += v3.z; a3.w += v3.w;
        }
        for (; r < e; ++r, p += HDIM) {
            const float4 v0 = *(const float4*)p;
            a0.x += v0.x; a0.y += v0.y; a0.z += v0.z; a0.w += v0.w;
        }

        const int cnt = e - s;
        const float inv = 1.0f / (float)(cnt > 1 ? cnt : 1);
        float4 m;
        m.x = (a0.x + a1.x + a2.x + a3.x) * inv;
        m.y = (a0.y + a1.y + a2.y + a3.y) * inv;
        m.z = (a0.z + a1.z + a2.z + a3.z) * inv;
        m.w = (a0.w + a1.w + a2.w + a3.w) * inv;
        *(float4*)(&s_mean[j][col4]) = m;
    }
    __syncthreads();

    // --- phase 2: logits = mean @ W^T + b, 8-bag register blocking ---
    const int c    = t & (CDIM - 1);
    const int half = t >> 7;
    const float* __restrict__ wrow = W + (size_t)c * HDIM + half * (HDIM / 2);

    float acc[BPB];
#pragma unroll
    for (int j = 0; j < BPB; ++j) acc[j] = 0.f;

    for (int hh = 0; hh < HDIM / 2; hh += 4) {
        const float4 wv = *(const float4*)(wrow + hh);
        const int hbase = half * (HDIM / 2) + hh;
#pragma unroll
        for (int j = 0; j < BPB; ++j) {
            acc[j] += s_mean[j][hbase + 0] * wv.x
                    + s_mean[j][hbase + 1] * wv.y
                    + s_mean[j][hbase + 2] * wv.z
                    + s_mean[j][hbase + 3] * wv.w;
        }
    }

#pragma unroll
    for (int j = 0; j < BPB; ++j) s_part[half][j][c] = acc[j];
    __syncthreads();

    for (int idx = t; idx < BPB * CDIM; idx += 256) {
        const int j  = idx >> 7;
        const int cc = idx & (CDIM - 1);
        out[(size_t)(g0 + j) * CDIM + cc] =
            s_part[0][j][cc] + s_part[1][j][cc] + b[cc];
    }
}

extern "C" void kernel_launch(void* const* d_in, const int* in_sizes, int n_in,
                              void* d_out, int out_size, void* d_ws, size_t ws_size,
                              hipStream_t stream) {
    const float* hidden = (const float*)d_in[0];
    const float* W      = (const float*)d_in[1];
    const float* b      = (const float*)d_in[2];
    const int*   bag_id = (const int*)d_in[3];
    float* out = (float*)d_out;
    const int N = in_sizes[3];  // 262144

    // PROBE: two identical launches. Kernel is deterministic and idempotent
    // (second launch rewrites identical values), so results are unchanged and
    // every call does the same work. X = dur(this round) - dur(round 2).
    bagre_kernel<<<NBAGS / BPB, 256, 0, stream>>>(hidden, W, b, bag_id, out, N);
    bagre_kernel<<<NBAGS / BPB, 256, 0, stream>>>(hidden, W, b, bag_id, out, N);
}

// Round 4
// 433.142 us; speedup vs baseline: 1.0319x; 1.0319x over previous
//
#include <hip/hip_runtime.h>

// BagRE: segment-mean over sorted bags + linear classifier.
//   hidden [N=262144, H=256] f32, W [C=128, H=256] f32, b [C] f32,
//   bag_id [N] i32 (sorted)  ->  out [NUM_BAGS=8192, C=128] f32
//
// R3 probe: X = 59.5 us = phase1 streaming (~39 us, at roofline) + phase2
// (~20 us, LDS-pipe-bound with HBM idle, phase-locked across the cohort).
// Fix: SPLIT. K1 = pure streaming means (no LDS, no barriers) -> d_ws.
// K2 = tiny GEMM, zero LDS: means read as wave-uniform (broadcast) global
// float4, W per-lane float4, acc in registers. K2 ~ 5 us VALU-bound.
// Calibration: harness overhead = 328.5 us; X = dur_us - 328.5.

#define NBAGS 8192
#define HDIM 256
#define CDIM 128

// ---------- kernel 1: per-bag means -> ws ----------
// grid 2048 x 256: wave q owns bag blockIdx*4+q. Lanes 0-1 binary-search the
// segment bounds (bag_id sorted), __shfl to the wave; lane holds 4 cols.
__global__ __launch_bounds__(256, 8) void bag_mean_kernel(
    const float* __restrict__ hidden,
    const int* __restrict__ bag_id,
    float* __restrict__ means,   // [NBAGS][HDIM]
    int N)
{
    const int q    = threadIdx.x >> 6;
    const int lane = threadIdx.x & 63;
    const int bag  = blockIdx.x * 4 + q;

    int bound = 0;
    if (lane < 2) {
        const int target = bag + lane;
        int lo = 0, hi = N;
        while (lo < hi) {
            const int mid = (lo + hi) >> 1;
            if (bag_id[mid] < target) lo = mid + 1; else hi = mid;
        }
        bound = lo;
    }
    const int s = __shfl(bound, 0);
    const int e = __shfl(bound, 1);

    const int col4 = lane << 2;
    float4 a0 = make_float4(0.f, 0.f, 0.f, 0.f);
    float4 a1 = a0, a2 = a0, a3 = a0;

    const float* __restrict__ p = hidden + (size_t)s * HDIM + col4;
    int r = s;
    for (; r + 4 <= e; r += 4, p += 4 * HDIM) {
        const float4 v0 = *(const float4*)(p + 0 * HDIM);
        const float4 v1 = *(const float4*)(p + 1 * HDIM);
        const float4 v2 = *(const float4*)(p + 2 * HDIM);
        const float4 v3 = *(const float4*)(p + 3 * HDIM);
        a0.x += v0.x; a0.y += v0.y; a0.z += v0.z; a0.w += v0.w;
        a1.x += v1.x; a1.y += v1.y; a1.z += v1.z; a1.w += v1.w;
        a2.x += v2.x; a2.y += v2.y; a2.z += v2.z; a2.w += v2.w;
        a3.x += v3.x; a3.y += v3.y; a3.z += v3.z; a3.w += v3.w;
    }
    for (; r < e; ++r, p += HDIM) {
        const float4 v0 = *(const float4*)p;
        a0.x += v0.x; a0.y += v0.y; a0.z += v0.z; a0.w += v0.w;
    }

    const int cnt = e - s;
    const float inv = 1.0f / (float)(cnt > 1 ? cnt : 1);
    float4 m;
    m.x = (a0.x + a1.x + a2.x + a3.x) * inv;
    m.y = (a0.y + a1.y + a2.y + a3.y) * inv;
    m.z = (a0.z + a1.z + a2.z + a3.z) * inv;
    m.w = (a0.w + a1.w + a2.w + a3.w) * inv;
    *(float4*)(means + (size_t)bag * HDIM + col4) = m;  // 1 KB/wave coalesced
}

// ---------- kernel 2: logits = means @ W^T + b ----------
// grid 1024 x 256, 8 bags/block. Thread t: class c = t&127, bag-group
// jg = t>>7 (wave-uniform). acc[4] over full K=256. Mean loads are
// wave-uniform (single-address broadcast, L1-hit); W float4 per-lane
// (L2-resident, 128 KB). No LDS, no barriers.
__global__ __launch_bounds__(256) void bag_logits_kernel(
    const float* __restrict__ means,
    const float* __restrict__ W,
    const float* __restrict__ b,
    float* __restrict__ out)
{
    const int t  = threadIdx.x;
    const int g0 = blockIdx.x * 8;
    const int c  = t & (CDIM - 1);
    const int jg = t >> 7;            // 0 or 1, wave-uniform
    const int j0 = jg * 4;

    const float* __restrict__ wrow = W + (size_t)c * HDIM;
    const float* __restrict__ m0 = means + (size_t)(g0 + j0 + 0) * HDIM;
    const float* __restrict__ m1 = means + (size_t)(g0 + j0 + 1) * HDIM;
    const float* __restrict__ m2 = means + (size_t)(g0 + j0 + 2) * HDIM;
    const float* __restrict__ m3 = means + (size_t)(g0 + j0 + 3) * HDIM;

    float acc0 = 0.f, acc1 = 0.f, acc2 = 0.f, acc3 = 0.f;
#pragma unroll 4
    for (int k = 0; k < HDIM; k += 4) {
        const float4 wv = *(const float4*)(wrow + k);
        const float4 u0 = *(const float4*)(m0 + k);
        const float4 u1 = *(const float4*)(m1 + k);
        const float4 u2 = *(const float4*)(m2 + k);
        const float4 u3 = *(const float4*)(m3 + k);
        acc0 += u0.x * wv.x + u0.y * wv.y + u0.z * wv.z + u0.w * wv.w;
        acc1 += u1.x * wv.x + u1.y * wv.y + u1.z * wv.z + u1.w * wv.w;
        acc2 += u2.x * wv.x + u2.y * wv.y + u2.z * wv.z + u2.w * wv.w;
        acc3 += u3.x * wv.x + u3.y * wv.y + u3.z * wv.z + u3.w * wv.w;
    }

    const float bias = b[c];
    out[(size_t)(g0 + j0 + 0) * CDIM + c] = acc0 + bias;
    out[(size_t)(g0 + j0 + 1) * CDIM + c] = acc1 + bias;
    out[(size_t)(g0 + j0 + 2) * CDIM + c] = acc2 + bias;
    out[(size_t)(g0 + j0 + 3) * CDIM + c] = acc3 + bias;
}

extern "C" void kernel_launch(void* const* d_in, const int* in_sizes, int n_in,
                              void* d_out, int out_size, void* d_ws, size_t ws_size,
                              hipStream_t stream) {
    const float* hidden = (const float*)d_in[0];
    const float* W      = (const float*)d_in[1];
    const float* b      = (const float*)d_in[2];
    const int*   bag_id = (const int*)d_in[3];
    float* out   = (float*)d_out;
    float* means = (float*)d_ws;      // 8192*256*4 = 8 MB scratch
    const int N = in_sizes[3];        // 262144

    bag_mean_kernel<<<NBAGS / 4, 256, 0, stream>>>(hidden, bag_id, means, N);
    bag_logits_kernel<<<NBAGS / 8, 256, 0, stream>>>(means, W, b, out);
}

// Round 5
// 409.878 us; speedup vs baseline: 1.0905x; 1.0568x over previous
//
#include <hip/hip_runtime.h>

// BagRE: segment-mean over sorted bags + linear classifier.
//   hidden [N=262144, H=256] f32, W [C=128, H=256] f32, b [C] f32,
//   bag_id [N] i32 (sorted)  ->  out [NUM_BAGS=8192, C=128] f32
//
// Calibration: harness overhead = 328.5 us; X = dur_us - 328.5.
// R4 lesson: X=105 (split regressed). (1) K2's per-lane W rows are 64-line
// scatters on the L1 port (~27 us) -> fix: stage W in LDS, XOR-swizzled,
// conflict-free b128 reads. (2) K1 with __launch_bounds__(256,8) (VGPR cap
// 64 -> spills?) + 1 bag/wave ran ~75 us vs R2-shape ~39 -> revert to exact
// R2 phase-1 structure (2 bags/wave, 8/block, no min-waves bound).

#define NBAGS 8192
#define HDIM 256
#define CDIM 128

// ---------- kernel 1: per-bag means -> ws (exact R2 phase-1 shape) ----------
__global__ __launch_bounds__(256) void bag_mean_kernel(
    const float* __restrict__ hidden,
    const int* __restrict__ bag_id,
    float* __restrict__ means,   // [NBAGS][HDIM]
    int N)
{
    __shared__ int s_bound[9];
    const int t  = threadIdx.x;
    const int g0 = blockIdx.x * 8;

    if (t <= 8) {
        const int target = g0 + t;
        int lo = 0, hi = N;
        while (lo < hi) {
            const int mid = (lo + hi) >> 1;
            if (bag_id[mid] < target) lo = mid + 1; else hi = mid;
        }
        s_bound[t] = lo;
    }
    __syncthreads();

    const int q    = t >> 6;
    const int lane = t & 63;
    const int col4 = lane << 2;

#pragma unroll
    for (int jj = 0; jj < 2; ++jj) {
        const int j = q * 2 + jj;
        const int s = s_bound[j];
        const int e = s_bound[j + 1];

        float4 a0 = make_float4(0.f, 0.f, 0.f, 0.f);
        float4 a1 = a0, a2 = a0, a3 = a0;

        const float* __restrict__ p = hidden + (size_t)s * HDIM + col4;
        int r = s;
        for (; r + 4 <= e; r += 4, p += 4 * HDIM) {
            const float4 v0 = *(const float4*)(p + 0 * HDIM);
            const float4 v1 = *(const float4*)(p + 1 * HDIM);
            const float4 v2 = *(const float4*)(p + 2 * HDIM);
            const float4 v3 = *(const float4*)(p + 3 * HDIM);
            a0.x += v0.x; a0.y += v0.y; a0.z += v0.z; a0.w += v0.w;
            a1.x += v1.x; a1.y += v1.y; a1.z += v1.z; a1.w += v1.w;
            a2.x += v2.x; a2.y += v2.y; a2.z += v2.z; a2.w += v2.w;
            a3.x += v3.x; a3.y += v3.y; a3.z += v3.z; a3.w += v3.w;
        }
        for (; r < e; ++r, p += HDIM) {
            const float4 v0 = *(const float4*)p;
            a0.x += v0.x; a0.y += v0.y; a0.z += v0.z; a0.w += v0.w;
        }

        const int cnt = e - s;
        const float inv = 1.0f / (float)(cnt > 1 ? cnt : 1);
        float4 m;
        m.x = (a0.x + a1.x + a2.x + a3.x) * inv;
        m.y = (a0.y + a1.y + a2.y + a3.y) * inv;
        m.z = (a0.z + a1.z + a2.z + a3.z) * inv;
        m.w = (a0.w + a1.w + a2.w + a3.w) * inv;
        *(float4*)(means + (size_t)(g0 + j) * HDIM + col4) = m;  // coalesced 1 KB
    }
}

// ---------- kernel 2: logits = means @ W^T + b ----------
// Block = 256 thr, handles 8 bags x 64 classes. blockIdx: bit0 = class-half,
// rest = bag-octet. W half staged in LDS (exactly 64 KB), XOR-swizzled so
// per-lane row reads are bank-conflict-free b128. Wave w: bags 2w,2w+1 over
// full K=256; lane = class. Means are wave-uniform broadcast loads (L1/L2).
// No scattered global loads anywhere; stores coalesced. 2 blocks/CU.
__global__ __launch_bounds__(256) void bag_logits_kernel(
    const float* __restrict__ means,
    const float* __restrict__ W,
    const float* __restrict__ b,
    float* __restrict__ out)
{
    __shared__ float wlds[64 * HDIM];   // 64 KB

    const int t     = threadIdx.x;
    const int chalf = blockIdx.x & 1;
    const int g0    = (blockIdx.x >> 1) * 8;

    // stage 64 classes of W: 16384 floats = 4096 float4, 16 per thread.
    // src is flat-contiguous -> perfectly coalesced. dst XOR-swizzle:
    // element (c,k) lives at c*256 + (k ^ ((c&7)<<2)).
    {
        const float* __restrict__ src = W + (size_t)chalf * 64 * HDIM;
#pragma unroll
        for (int i = 0; i < 16; ++i) {
            const int fi = i * 256 + t;      // float4 index
            const int f  = fi << 2;          // float index 0..16383
            const int cl = f >> 8;           // local class 0..63
            const int k  = f & 255;          // 4-aligned
            const float4 v = *(const float4*)(src + f);
            *(float4*)(&wlds[cl * HDIM + (k ^ ((cl & 7) << 2))]) = v;
        }
    }
    __syncthreads();

    const int wv   = t >> 6;           // wave 0..3 -> bags 2wv, 2wv+1
    const int lane = t & 63;           // local class
    const int cg   = chalf * 64 + lane;

    const float* __restrict__ m0 = means + (size_t)(g0 + 2 * wv) * HDIM;
    const float* __restrict__ m1 = m0 + HDIM;
    const float* __restrict__ wrow = wlds + lane * HDIM;
    const int sw = (lane & 7) << 2;

    float acc0 = 0.f, acc1 = 0.f;
#pragma unroll 4
    for (int k = 0; k < HDIM; k += 4) {
        const float4 wv4 = *(const float4*)(wrow + (k ^ sw));  // conflict-free
        const float4 u0  = *(const float4*)(m0 + k);           // broadcast
        const float4 u1  = *(const float4*)(m1 + k);           // broadcast
        acc0 += u0.x * wv4.x + u0.y * wv4.y + u0.z * wv4.z + u0.w * wv4.w;
        acc1 += u1.x * wv4.x + u1.y * wv4.y + u1.z * wv4.z + u1.w * wv4.w;
    }

    const float bias = b[cg];
    out[(size_t)(g0 + 2 * wv)     * CDIM + cg] = acc0 + bias;  // coalesced
    out[(size_t)(g0 + 2 * wv + 1) * CDIM + cg] = acc1 + bias;  // coalesced
}

extern "C" void kernel_launch(void* const* d_in, const int* in_sizes, int n_in,
                              void* d_out, int out_size, void* d_ws, size_t ws_size,
                              hipStream_t stream) {
    const float* hidden = (const float*)d_in[0];
    const float* W      = (const float*)d_in[1];
    const float* b      = (const float*)d_in[2];
    const int*   bag_id = (const int*)d_in[3];
    float* out   = (float*)d_out;
    float* means = (float*)d_ws;      // 8 MB scratch
    const int N = in_sizes[3];        // 262144

    bag_mean_kernel<<<NBAGS / 8, 256, 0, stream>>>(hidden, bag_id, means, N);
    bag_logits_kernel<<<(NBAGS / 8) * 2, 256, 0, stream>>>(means, W, b, out);
}